// Round 4
// baseline (10.759 us; speedup 1.0000x reference)
//
#include <hip/hip_runtime.h>
#include <hip/hip_bf16.h>

// out[b,u] = tanh( sum_f inputs[b, T-1, f] * kernel[f,u] + bias[u] )
// B=256, T=512, F=256, U=256, fp32.
//
// Grid: 256 blocks (1/CU) x 256 threads (4 waves).
// Block tile: 8 b-rows x 32 u-cols  (btile = blk&31 -> b0 = btile*8,
//                                    utile = blk>>5 -> u0 = utile*32).
//   -> per-block kern traffic = 256f x 32u x 4B = 32 KB; total L2 traffic
//      8 MB (vs 64 MB in round 3, which was ~1.9us at the L2 ceiling).
// f-split across the 4 waves (wave w covers f in [w*64, w*64+64)).
// Lane: bhat = lane>>3 (one of 8 b-rows), u4 = lane&7 (one float4 of u).
// Per wave: 4 batches of 16 float4 kern loads, double-buffered
// (16+16 = 128 VGPRs in flight -- the no-spill budget from round 2's lesson).
// x staged in LDS, rows padded +4 floats so the 8 bhat broadcast-read
// addresses hit distinct bank groups (else 8-way conflict).
// Wave partials combine via LDS + one __syncthreads, then bias + tanh.

#define T_DIM 512
#define F_DIM 256
#define U_DIM 256
#define XPAD  4

__global__ __launch_bounds__(256) void lastslice_matmul_tanh(
    const float* __restrict__ inputs,   // [B, T, F]
    const float* __restrict__ kern,     // [F, U]
    const float* __restrict__ bias,     // [U]
    float* __restrict__ out)            // [B, U]
{
    const int tid  = threadIdx.x;
    const int lane = tid & 63;
    const int w    = tid >> 6;          // wave id 0..3 -> f-chunk
    const int blk  = blockIdx.x;
    const int b0   = (blk & 31) * 8;
    const int u0   = (blk >> 5) * 32;
    const int bhat = lane >> 3;         // 0..7: b-row within tile
    const int u4   = lane & 7;          // 0..7: float4-col within 32-u tile

    __shared__ __align__(16) float xs[8][F_DIM + XPAD];  // ~8.1 KB
    __shared__ __align__(16) float part[4][8][32];       // 4 KB

    const float* kbase = kern + (size_t)(w * 64) * U_DIM + u0 + u4 * 4;

    // Issue kern batch 0 ASAP (overlaps x staging latency).
    float4 A[16], Bb[16];
    #pragma unroll
    for (int j = 0; j < 16; ++j)
        A[j] = *(const float4*)(kbase + (size_t)j * U_DIM);

    // Stage 8 last-timestep x-rows: 512 float4, 2 per thread.
    // Wave w writes full rows (idx>>6 is constant per wave per k).
    #pragma unroll
    for (int k = 0; k < 2; ++k) {
        int idx = tid + k * 256;        // float4 index over [8][64]
        int r = idx >> 6, c = idx & 63;
        const float4* src = (const float4*)(inputs +
            ((size_t)(b0 + r) * T_DIM + (T_DIM - 1)) * F_DIM);
        ((float4*)&xs[r][0])[c] = src[c];
    }
    __syncthreads();

    float4 acc = make_float4(0.f, 0.f, 0.f, 0.f);
    const float4* xrow4 = (const float4*)&xs[bhat][w * 64];

    #pragma unroll
    for (int t = 0; t < 4; ++t) {
        if (t < 3) {
            #pragma unroll
            for (int j = 0; j < 16; ++j)
                ((t & 1) ? A : Bb)[j] =
                    *(const float4*)(kbase + (size_t)((t + 1) * 16 + j) * U_DIM);
        }
        const float4* cur = (t & 1) ? Bb : A;
        #pragma unroll
        for (int j4 = 0; j4 < 4; ++j4) {
            const float4 xq = xrow4[t * 4 + j4];
            const float xv[4] = {xq.x, xq.y, xq.z, xq.w};
            #pragma unroll
            for (int jj = 0; jj < 4; ++jj) {
                const float4 kv = cur[j4 * 4 + jj];
                acc.x = fmaf(xv[jj], kv.x, acc.x);
                acc.y = fmaf(xv[jj], kv.y, acc.y);
                acc.z = fmaf(xv[jj], kv.z, acc.z);
                acc.w = fmaf(xv[jj], kv.w, acc.w);
            }
        }
    }

    // Combine the 4 waves' partials: each wave writes its full 1 KB plane.
    *(float4*)&part[w][bhat][u4 * 4] = acc;
    __syncthreads();

    const int r  = tid >> 5;            // 0..7  b-row
    const int uc = tid & 31;            // 0..31 u-col
    float s = part[0][r][uc] + part[1][r][uc] + part[2][r][uc] + part[3][r][uc]
            + bias[u0 + uc];
    out[(size_t)(b0 + r) * U_DIM + u0 + uc] = tanhf(s);
}

extern "C" void kernel_launch(void* const* d_in, const int* in_sizes, int n_in,
                              void* d_out, int out_size, void* d_ws, size_t ws_size,
                              hipStream_t stream) {
    const float* inputs = (const float*)d_in[0];   // B*T*F
    const float* kern   = (const float*)d_in[1];   // F*U
    const float* bias   = (const float*)d_in[2];   // U
    float* out          = (float*)d_out;           // B*U

    dim3 grid(256);
    dim3 block(256);
    lastslice_matmul_tanh<<<grid, block, 0, stream>>>(inputs, kern, bias, out);
}

// Round 5
// 9.776 us; speedup vs baseline: 1.1004x; 1.1004x over previous
//
#include <hip/hip_runtime.h>
#include <hip/hip_bf16.h>

// out[b,u] = tanh( sum_f inputs[b, T-1, f] * kernel[f,u] + bias[u] )
// B=256, T=512, F=256, U=256, fp32.
//
// Round-3 structure (best measured: 9.60 us) reverted after R4's 8bx32u
// tiling regressed to 10.76 us (L2 kern re-reads were NOT the binding
// constraint; bench is launch-overhead dominated, noise ~±1 us).
//
// Grid: 256 blocks (one per b) x 256 threads (4 waves).
// Wave w handles f-rows [w*64, w*64+64); lane covers u = lane*4 .. lane*4+3
// (float4 kernel loads, fully coalesced: 1 KB per wave per f-row).
// Per wave: 4 batches of 16 float4 loads, double-buffered (16+16 = 128 VGPRs
// in flight -- the no-spill budget learned in round 2; 256-VGPR cap = spill).
// Only change vs R3: dropped the __syncthreads after x staging -- xs[w] is
// written and read by the SAME wave only (compiler's lgkmcnt orders it);
// the barrier before the partial-combine remains.

#define T_DIM 512
#define F_DIM 256
#define U_DIM 256

__global__ __launch_bounds__(256) void lastslice_matmul_tanh(
    const float* __restrict__ inputs,   // [B, T, F]
    const float* __restrict__ kern,     // [F, U]
    const float* __restrict__ bias,     // [U]
    float* __restrict__ out)            // [B, U]
{
    const int tid  = threadIdx.x;
    const int lane = tid & 63;
    const int w    = tid >> 6;          // wave id 0..3 -> f-chunk
    const int b    = blockIdx.x;
    const int u0   = lane * 4;

    __shared__ __align__(16) float xs[4][64];     // wave-private x chunks
    __shared__ __align__(16) float part[4][U_DIM];

    // Stage this wave's 64 x-values (same-wave LDS RAW: no barrier needed).
    const float* xrow = inputs + ((size_t)b * T_DIM + (T_DIM - 1)) * F_DIM;
    xs[w][lane] = xrow[w * 64 + lane];

    const float* kbase = kern + (size_t)(w * 64) * U_DIM + u0;

    // Batch 0 into A.
    float4 A[16], Bb[16];
    #pragma unroll
    for (int j = 0; j < 16; ++j)
        A[j] = *(const float4*)(kbase + (size_t)j * U_DIM);

    float4 acc = make_float4(0.f, 0.f, 0.f, 0.f);

    #pragma unroll
    for (int t = 0; t < 4; ++t) {
        // Prefetch next batch into the other buffer (static after unroll).
        if (t < 3) {
            #pragma unroll
            for (int j = 0; j < 16; ++j)
                ((t & 1) ? A : Bb)[j] =
                    *(const float4*)(kbase + (size_t)((t + 1) * 16 + j) * U_DIM);
        }
        const float4* cur = (t & 1) ? Bb : A;
        #pragma unroll
        for (int j4 = 0; j4 < 4; ++j4) {
            const float4 xq = ((const float4*)&xs[w][0])[t * 4 + j4];
            const float xv[4] = {xq.x, xq.y, xq.z, xq.w};
            #pragma unroll
            for (int jj = 0; jj < 4; ++jj) {
                const float4 kv = cur[j4 * 4 + jj];
                acc.x = fmaf(xv[jj], kv.x, acc.x);
                acc.y = fmaf(xv[jj], kv.y, acc.y);
                acc.z = fmaf(xv[jj], kv.z, acc.z);
                acc.w = fmaf(xv[jj], kv.w, acc.w);
            }
        }
    }

    // Combine the 4 waves' partials.
    *(float4*)&part[w][u0] = acc;
    __syncthreads();

    const int u = tid;                  // 0..255
    float s = part[0][u] + part[1][u] + part[2][u] + part[3][u] + bias[u];
    out[(size_t)b * U_DIM + u] = tanhf(s);
}

extern "C" void kernel_launch(void* const* d_in, const int* in_sizes, int n_in,
                              void* d_out, int out_size, void* d_ws, size_t ws_size,
                              hipStream_t stream) {
    const float* inputs = (const float*)d_in[0];   // B*T*F
    const float* kern   = (const float*)d_in[1];   // F*U
    const float* bias   = (const float*)d_in[2];   // U
    float* out          = (float*)d_out;           // B*U

    dim3 grid(256);
    dim3 block(256);
    lastslice_matmul_tanh<<<grid, block, 0, stream>>>(inputs, kern, bias, out);
}